// Round 18
// baseline (177.898 us; speedup 1.0000x reference)
//
#include <hip/hip_runtime.h>
#include <math.h>

#define BATCH 512
#define DIM   1024
#define NCLUS 16384
#define TINV  20.0f   // 1/TEMP

typedef __attribute__((ext_vector_type(4))) float f32x4;
typedef __attribute__((ext_vector_type(2))) float f32x2;
typedef __attribute__((ext_vector_type(8))) short bf16x8;
typedef __attribute__((ext_vector_type(4))) unsigned int u32x4;

static __device__ __forceinline__ unsigned short f2bf(float f) {
  unsigned int u = __float_as_uint(f);
  u += 0x7FFFu + ((u >> 16) & 1u);   // round-to-nearest-even
  return (unsigned short)(u >> 16);
}

typedef const __attribute__((address_space(1))) unsigned int* gas1_t;
typedef __attribute__((address_space(3))) unsigned int* las3_t;
// async global->LDS, 16B per lane; LDS dest = wave-uniform base + lane*16
static __device__ __forceinline__ void gload16(const void* g, void* l) {
  __builtin_amdgcn_global_load_lds((gas1_t)g, (las3_t)l, 16, 0, 0);
}

// ---------------------------------------------------------------------------
// Kernel 1: row L2-normalize (both modalities), emit f32 + bf16 copies of x.
// Also zeroes the 2048-float accumulator region (rowsum + tgtlog).
// ---------------------------------------------------------------------------
__global__ void nrm_kernel(const float* __restrict__ in_rgb,
                           const float* __restrict__ in_ir,
                           float* __restrict__ xf,            // [2][512][1024]
                           unsigned short* __restrict__ xb,   // [2][512][1024]
                           float* __restrict__ accum) {       // 2048 floats
  int gid = blockIdx.x * blockDim.x + threadIdx.x;
  if (gid < 2048) accum[gid] = 0.0f;

  int row = blockIdx.x;
  int mod = row >> 9;
  int r   = row & 511;
  const float* in = (mod ? in_ir : in_rgb) + (size_t)r * DIM;
  float* xo          = xf + ((size_t)mod * BATCH + r) * DIM;
  unsigned short* xbo = xb + ((size_t)mod * BATCH + r) * DIM;

  int t = threadIdx.x;
  float4 v = ((const float4*)in)[t];
  float ss = v.x*v.x + v.y*v.y + v.z*v.z + v.w*v.w;
#pragma unroll
  for (int m = 1; m < 64; m <<= 1) ss += __shfl_xor(ss, m, 64);
  __shared__ float red[4];
  if ((t & 63) == 0) red[t >> 6] = ss;
  __syncthreads();
  float inv = 1.0f / fmaxf(sqrtf(red[0] + red[1] + red[2] + red[3]), 1e-12f);
  float4 o = make_float4(v.x * inv, v.y * inv, v.z * inv, v.w * inv);
  ((float4*)xo)[t] = o;
  ushort4 ob = make_ushort4(f2bf(o.x), f2bf(o.y), f2bf(o.z), f2bf(o.w));
  ((ushort4*)xbo)[t] = ob;
}

// ---------------------------------------------------------------------------
// Kernel 2: FUSED 128x128 bf16 MFMA GEMM + in-loop bank copy + exp-sum/target.
// R12/R17 winning structure (167-171 us) with ONE parameter change: BK 32->64.
// Mechanism: the loop is a latency convoy (~const exposed latency per barrier
// interval); halving the interval count (32->16) halves total exposed latency.
// Cost: LDS 32->64 KB -> 2 blocks/CU.
//  - A: async gload_lds, swizzled pair for 128B rows: source chunk
//    cs=(q&7)^(row&7) into linear dest; read chunk (h*4+lhi)^(row&7).
//  - B: f32 panel -> regs (8x f32x4, same-iteration live range only),
//    truncate-pack, ds_write at chunk j^(row&7). Uniform 8-dword/bank.
//  - copy: 2 f32x4 chunks per iteration (quarter panel over 16 iters).
//  - gate: B_WRITE's implicit wait retires craw+B; vmcnt(4) retires A(4),
//    keeps the 4 copy-stores in flight across the barrier (T4-correct).
// grid (128 nt, 8 = mod*4+bt): linear idx % 8 == nt % 8 -> panel blocks
// share an XCD (B-path + copy-path L2 reuse).
// ---------------------------------------------------------------------------
#define BM 128
#define BN 128
#define BK 64
#define KT_N (DIM / BK)   // 16

__launch_bounds__(256, 2)
__global__ void gemm_lse_kernel(const unsigned short* __restrict__ xb,
                                const float* __restrict__ f_rgb,
                                const float* __restrict__ f_ir,
                                const int* __restrict__ t_rgb,
                                const int* __restrict__ t_ir,
                                float* __restrict__ outc,     // d_out + 2
                                float* __restrict__ rowsum,   // [2][512]
                                float* __restrict__ tgtlog) { // [2][512]
  const int nt  = blockIdx.x;        // 0..127
  const int bt  = blockIdx.y & 3;    // batch tile
  const int mod = blockIdx.y >> 2;   // modality

  const unsigned short* X = xb + ((size_t)mod * BATCH + bt * BM) * DIM;
  const float* Ff = (mod ? f_ir : f_rgb) + (size_t)nt * BN * DIM;   // panel
  const float* Fq = Ff + (size_t)bt * 32 * DIM;                     // quarter
  float* Oq = outc + ((size_t)mod * NCLUS + (size_t)nt * BN + bt * 32) * DIM;
  const int* tg = mod ? t_ir : t_rgb;
  float* rs = rowsum + mod * BATCH;
  float* tl = tgtlog + mod * BATCH;

  __shared__ __align__(16) unsigned short As[2][BM * BK];  // 32 KB
  __shared__ __align__(16) unsigned short Bs[2][BM * BK];  // 32 KB

  const int tid  = threadIdx.x;
  const int wid  = tid >> 6;
  const int lane = tid & 63;
  const int wr = wid >> 1, wc = wid & 1;
  const int l15 = lane & 15, lhi = lane >> 4;

  f32x4 acc[4][4];
#pragma unroll
  for (int m = 0; m < 4; ++m)
#pragma unroll
    for (int n = 0; n < 4; ++n) acc[m][n] = (f32x4){0.f, 0.f, 0.f, 0.f};

  // A: 128 rows x 64 bf16 (128B rows, 8 chunks/row). Source chunk
  // cs=(q&7)^(row&7) into linear dest; 4 gload16/thread.
  auto A_STAGE = [&](int buf, int kt) {
#pragma unroll
    for (int c = 0; c < 4; ++c) {
      int q = c * 256 + tid;                    // 16B chunk 0..1023
      int row = q >> 3;
      int cs = (q & 7) ^ (row & 7);
      gload16(X + (size_t)row * DIM + kt * BK + cs * 8,
              &As[buf][(c * 256 + wid * 64) * 8]);
    }
  };
  // B: f32 panel rows -> regs; 8 f32x4/thread (chunk h=(row,j), j=bf16-16B)
  auto B_LOAD = [&](f32x4* br, int kk) {
#pragma unroll
    for (int c = 0; c < 4; ++c) {
      int h = c * 256 + tid, row = h >> 3, j = h & 7;
      const float* sp = Ff + (size_t)row * DIM + kk + j * 8;
      br[c * 2]     = *(const f32x4*)sp;
      br[c * 2 + 1] = *(const f32x4*)(sp + 4);
    }
  };
  // truncate-pack + ds_write at swizzled chunk j^(row&7)
  auto B_WRITE = [&](int buf, const f32x4* br) {
#pragma unroll
    for (int c = 0; c < 4; ++c) {
      int h = c * 256 + tid, row = h >> 3, j = h & 7;
      u32x4 p;
      p.x = (__float_as_uint(br[c*2].x)   >> 16) | (__float_as_uint(br[c*2].y)   & 0xFFFF0000u);
      p.y = (__float_as_uint(br[c*2].z)   >> 16) | (__float_as_uint(br[c*2].w)   & 0xFFFF0000u);
      p.z = (__float_as_uint(br[c*2+1].x) >> 16) | (__float_as_uint(br[c*2+1].y) & 0xFFFF0000u);
      p.w = (__float_as_uint(br[c*2+1].z) >> 16) | (__float_as_uint(br[c*2+1].w) & 0xFFFF0000u);
      *(u32x4*)((char*)&Bs[buf][0] + row * 128 + ((j ^ (row & 7)) << 4)) = p;
    }
  };
  // fragment read: k-slice h (0/1), chunk = (h*4+lhi)^(row&7)
  auto LDF = [&](const unsigned short* base, int row, int h) {
    int chunk = ((h << 2) | lhi) ^ (row & 7);
    return *(const bf16x8*)((const char*)base + row * 128 + (chunk << 4));
  };
  auto COMPUTE = [&](int buf) {
    bf16x8 a0[4], a1[4], b0[4], b1[4];
#pragma unroll
    for (int n = 0; n < 4; ++n) {
      const int row = wc * 64 + n * 16 + l15;
      b0[n] = LDF(Bs[buf], row, 0);
      b1[n] = LDF(Bs[buf], row, 1);
    }
#pragma unroll
    for (int m = 0; m < 4; ++m) {
      const int row = wr * 64 + m * 16 + l15;
      a0[m] = LDF(As[buf], row, 0);
      a1[m] = LDF(As[buf], row, 1);
    }
#pragma unroll
    for (int m = 0; m < 4; ++m)
#pragma unroll
      for (int n = 0; n < 4; ++n) {
        acc[m][n] = __builtin_amdgcn_mfma_f32_16x16x32_bf16(a0[m], b0[n], acc[m][n], 0, 0, 0);
        acc[m][n] = __builtin_amdgcn_mfma_f32_16x16x32_bf16(a1[m], b1[n], acc[m][n], 0, 0, 0);
      }
  };

  // prologue: K-tile 0, full drain once
  {
    f32x4 br0[8];
    B_LOAD(br0, 0);
    A_STAGE(0, 0);
    B_WRITE(0, br0);
  }
  __syncthreads();

  for (int s = 0; s < KT_N; ++s) {
    const int cur = s & 1;
    // ---- issue phase ----
    const int id0 = s * 512 + tid;                // copy: 2 chunks/iter
    const int id1 = id0 + 256;
    f32x4 craw0 = *((const f32x4*)Fq + (size_t)(id0 >> 8) * 256 + (id0 & 255));
    f32x4 craw1 = *((const f32x4*)Fq + (size_t)(id1 >> 8) * 256 + (id1 & 255));
    f32x4 braw[8];
    if (s + 1 < KT_N) {
      B_LOAD(braw, (s + 1) * BK);
      A_STAGE(cur ^ 1, s + 1);
    }
    __builtin_amdgcn_sched_barrier(0);
    // ---- compute on resident buffers (loads in flight above) ----
    COMPUTE(cur);
    if (s + 1 < KT_N) B_WRITE(cur ^ 1, braw);     // implicit wait: B+craw retired
    // ---- copy stores (newest VMEM ops) ----
    {
      float* dp0 = Oq + (size_t)(id0 >> 8) * DIM + (size_t)(id0 & 255) * 4;
      float* dp1 = Oq + (size_t)(id1 >> 8) * DIM + (size_t)(id1 & 255) * 4;
      __builtin_nontemporal_store((f32x2){craw0.x, craw0.y}, (f32x2*)dp0);
      __builtin_nontemporal_store((f32x2){craw0.z, craw0.w}, (f32x2*)(dp0 + 2));
      __builtin_nontemporal_store((f32x2){craw1.x, craw1.y}, (f32x2*)dp1);
      __builtin_nontemporal_store((f32x2){craw1.z, craw1.w}, (f32x2*)(dp1 + 2));
    }
    if (s + 1 < KT_N) {
      // counted gate: retire A-stage (4), keep the 4 copy-stores in flight
      asm volatile("s_waitcnt vmcnt(4) lgkmcnt(0)" ::: "memory");
      __builtin_amdgcn_sched_barrier(0);
      __builtin_amdgcn_s_barrier();
    }
  }

  // epilogue: exp-sum over this tile's 128 cols + target capture (verified)
#pragma unroll
  for (int m = 0; m < 4; ++m) {
    const int browbase = bt * BM + wr * 64 + m * 16 + lhi * 4;
    float esum[4];
#pragma unroll
    for (int j = 0; j < 4; ++j) {
      const int brow = browbase + j;
      const int t = tg[brow];
      float e = 0.f;
#pragma unroll
      for (int n = 0; n < 4; ++n) {
        float logit = acc[m][n][j] * TINV;
        e += __expf(logit);
        int col = nt * BN + wc * 64 + n * 16 + l15;
        if (col == t) tl[brow] = logit;
      }
      esum[j] = e;
    }
#pragma unroll
    for (int j = 0; j < 4; ++j) {
      float e = esum[j];
      e += __shfl_xor(e, 1, 64);
      e += __shfl_xor(e, 2, 64);
      e += __shfl_xor(e, 4, 64);
      e += __shfl_xor(e, 8, 64);
      if (l15 == 0) atomicAdd(rs + browbase + j, e);
    }
  }
}

// ---------------------------------------------------------------------------
// Kernel 3: loss = mean(log(rowsum) - tgtlog) per modality
// ---------------------------------------------------------------------------
__global__ void loss_kernel(const float* __restrict__ rowsum,
                            const float* __restrict__ tgtlog,
                            float* __restrict__ out) {
  int t = threadIdx.x;  // 512
  float lr = logf(rowsum[t]) - tgtlog[t];
  float li = logf(rowsum[BATCH + t]) - tgtlog[BATCH + t];
#pragma unroll
  for (int m = 1; m < 64; m <<= 1) { lr += __shfl_xor(lr, m, 64); li += __shfl_xor(li, m, 64); }
  __shared__ float sr[8], si[8];
  if ((t & 63) == 0) { sr[t >> 6] = lr; si[t >> 6] = li; }
  __syncthreads();
  if (t == 0) {
    float a = 0.f, b = 0.f;
#pragma unroll
    for (int i = 0; i < 8; ++i) { a += sr[i]; b += si[i]; }
    out[0] = a * (1.0f / BATCH);
    out[1] = b * (1.0f / BATCH);
  }
}

// ---------------------------------------------------------------------------
// Kernel 4: sequential momentum update chains on the copied banks.
// ---------------------------------------------------------------------------
__global__ void mom_kernel(const int* __restrict__ t_rgb,
                           const int* __restrict__ t_ir,
                           const float* __restrict__ xf,   // [2][512][1024]
                           float* __restrict__ out) {      // out + 2 base
  const int i   = blockIdx.x;
  const int mod = blockIdx.y;
  const int* tg = mod ? t_ir : t_rgb;
  const int y = tg[i];
  for (int j = 0; j < i; ++j)
    if (tg[j] == y) return;          // uniform: another block owns this chain

  const float* x = xf + (size_t)mod * BATCH * DIM;
  float* rowp = out + (size_t)mod * NCLUS * DIM + (size_t)y * DIM;

  const int t = threadIdx.x;  // 256
  float2 r0 = ((const float2*)rowp)[t];
  float2 r1 = ((const float2*)rowp)[t + 256];
  __shared__ float red[4];

  for (int j = i; j < BATCH; ++j) {
    if (tg[j] != y) continue;        // uniform
    const float2* xr = (const float2*)(x + (size_t)j * DIM);
    float2 x0 = xr[t], x1 = xr[t + 256];
    r0.x = 0.9f * r0.x + 0.1f * x0.x;
    r0.y = 0.9f * r0.y + 0.1f * x0.y;
    r1.x = 0.9f * r1.x + 0.1f * x1.x;
    r1.y = 0.9f * r1.y + 0.1f * x1.y;
    float ss = r0.x*r0.x + r0.y*r0.y + r1.x*r1.x + r1.y*r1.y;
#pragma unroll
    for (int m = 1; m < 64; m <<= 1) ss += __shfl_xor(ss, m, 64);
    if ((t & 63) == 0) red[t >> 6] = ss;
    __syncthreads();
    float tot = red[0] + red[1] + red[2] + red[3];
    __syncthreads();
    float inv = 1.0f / sqrtf(tot);
    r0.x *= inv; r0.y *= inv; r1.x *= inv; r1.y *= inv;
  }
  ((float2*)rowp)[t] = r0;
  ((float2*)rowp)[t + 256] = r1;
}

// ---------------------------------------------------------------------------
extern "C" void kernel_launch(void* const* d_in, const int* in_sizes, int n_in,
                              void* d_out, int out_size, void* d_ws, size_t ws_size,
                              hipStream_t stream) {
  (void)in_sizes; (void)n_in; (void)out_size; (void)ws_size;
  const float* in_rgb = (const float*)d_in[0];
  const float* in_ir  = (const float*)d_in[1];
  const int*   t_rgb  = (const int*)d_in[2];
  const int*   t_ir   = (const int*)d_in[3];
  const float* f_rgb  = (const float*)d_in[4];
  const float* f_ir   = (const float*)d_in[5];
  float* out = (float*)d_out;

  char* ws = (char*)d_ws;
  float*          xf     = (float*)ws;                       // 4 MB  [2][512][1024] f32
  unsigned short* xb     = (unsigned short*)(ws + (4u<<20)); // 2 MB  [2][512][1024] bf16
  float*          rowsum = (float*)(ws + (6u<<20));          // 2048 f32 (rowsum+tgtlog)
  float*          tgtlog = rowsum + 1024;

  nrm_kernel<<<1024, 256, 0, stream>>>(in_rgb, in_ir, xf, xb, rowsum);
  gemm_lse_kernel<<<dim3(128, 8), 256, 0, stream>>>(xb, f_rgb, f_ir, t_rgb, t_ir,
                                                    out + 2, rowsum, tgtlog);
  mom_kernel<<<dim3(512, 2), 256, 0, stream>>>(t_rgb, t_ir, xf, out + 2);
  loss_kernel<<<1, 512, 0, stream>>>(rowsum, tgtlog, out);
}

// Round 19
// 170.112 us; speedup vs baseline: 1.0458x; 1.0458x over previous
//
#include <hip/hip_runtime.h>
#include <math.h>

#define BATCH 512
#define DIM   1024
#define NCLUS 16384
#define TINV  20.0f   // 1/TEMP

typedef __attribute__((ext_vector_type(4))) float f32x4;
typedef __attribute__((ext_vector_type(2))) float f32x2;
typedef __attribute__((ext_vector_type(8))) short bf16x8;

static __device__ __forceinline__ unsigned short f2bf(float f) {
  unsigned int u = __float_as_uint(f);
  u += 0x7FFFu + ((u >> 16) & 1u);   // round-to-nearest-even
  return (unsigned short)(u >> 16);
}

typedef const __attribute__((address_space(1))) unsigned int* gas1_t;
typedef __attribute__((address_space(3))) unsigned int* las3_t;
// async global->LDS, 16B per lane; LDS dest = wave-uniform base + lane*16
static __device__ __forceinline__ void gload16(const void* g, void* l) {
  __builtin_amdgcn_global_load_lds((gas1_t)g, (las3_t)l, 16, 0, 0);
}

// ---------------------------------------------------------------------------
// Kernel 1: row L2-normalize (both modalities), emit f32 + bf16 copies of x.
// Also zeroes the 2048-float accumulator region (rowsum + tgtlog).
// ---------------------------------------------------------------------------
__global__ void nrm_kernel(const float* __restrict__ in_rgb,
                           const float* __restrict__ in_ir,
                           float* __restrict__ xf,            // [2][512][1024]
                           unsigned short* __restrict__ xb,   // [2][512][1024]
                           float* __restrict__ accum) {       // 2048 floats
  int gid = blockIdx.x * blockDim.x + threadIdx.x;
  if (gid < 2048) accum[gid] = 0.0f;

  int row = blockIdx.x;
  int mod = row >> 9;
  int r   = row & 511;
  const float* in = (mod ? in_ir : in_rgb) + (size_t)r * DIM;
  float* xo          = xf + ((size_t)mod * BATCH + r) * DIM;
  unsigned short* xbo = xb + ((size_t)mod * BATCH + r) * DIM;

  int t = threadIdx.x;
  float4 v = ((const float4*)in)[t];
  float ss = v.x*v.x + v.y*v.y + v.z*v.z + v.w*v.w;
#pragma unroll
  for (int m = 1; m < 64; m <<= 1) ss += __shfl_xor(ss, m, 64);
  __shared__ float red[4];
  if ((t & 63) == 0) red[t >> 6] = ss;
  __syncthreads();
  float inv = 1.0f / fmaxf(sqrtf(red[0] + red[1] + red[2] + red[3]), 1e-12f);
  float4 o = make_float4(v.x * inv, v.y * inv, v.z * inv, v.w * inv);
  ((float4*)xo)[t] = o;
  ushort4 ob = make_ushort4(f2bf(o.x), f2bf(o.y), f2bf(o.z), f2bf(o.w));
  ((ushort4*)xbo)[t] = ob;
}

// ---------------------------------------------------------------------------
// Kernel 2: FUSED 128x128 bf16 MFMA GEMM + in-loop bank copy + exp-sum/target.
// FINAL configuration (verified 167.3/171.1 us total, rounds 12/17):
//  (1) B straight from f32 F: 4x f32x4 global->reg, truncate-pack to bf16,
//      ds_write into the verified swizzled layout (chunk pos = j^((row>>1)&3);
//      read byte ^ (l15&6)<<3; SQ_LDS_BANK_CONFLICT = 0). No fb buffer, no
//      cvtcopy kernel.
//  (2) each block copies its quarter F-panel to d_out, ONE f32x4 chunk per
//      K-iteration, counted gate vmcnt(2): retires A-stage, keeps the 2
//      copy-stores in flight across the barrier.
//  (3) __launch_bounds__(256,4), 32KB LDS -> 4 blocks/CU.
// Neighborhood all measured worse: BK=64 (R18: 177.9, occupancy halves),
// 256² tiles (R8-R11: 90-100us gemm), cross-barrier B regs spill to scratch
// (R13: 404, R14: 313 — NO register state across asm-gate clusters),
// B-via-LDS-f32 (R15: 178.8), post-loop copy burst (R16: 181.7),
// CU-partitioned roles (R10: 335), in-syncthreads-loop stores (R6: 195).
// This point is the measured optimum of the explored structure family.
// grid (128 nt, 8 = mod*4+bt): linear idx % 8 == nt % 8 -> panel blocks
// share an XCD (B-path + copy-path L2 reuse).
// ---------------------------------------------------------------------------
#define BM 128
#define BN 128
#define BK 32
#define KT_N (DIM / BK)   // 32

__launch_bounds__(256, 4)
__global__ void gemm_lse_kernel(const unsigned short* __restrict__ xb,
                                const float* __restrict__ f_rgb,
                                const float* __restrict__ f_ir,
                                const int* __restrict__ t_rgb,
                                const int* __restrict__ t_ir,
                                float* __restrict__ outc,     // d_out + 2
                                float* __restrict__ rowsum,   // [2][512]
                                float* __restrict__ tgtlog) { // [2][512]
  const int nt  = blockIdx.x;        // 0..127
  const int bt  = blockIdx.y & 3;    // batch tile
  const int mod = blockIdx.y >> 2;   // modality

  const unsigned short* X = xb + ((size_t)mod * BATCH + bt * BM) * DIM;
  const float* Ff = (mod ? f_ir : f_rgb) + (size_t)nt * BN * DIM;   // panel
  const float* Fq = Ff + (size_t)bt * 32 * DIM;                     // quarter
  float* Oq = outc + ((size_t)mod * NCLUS + (size_t)nt * BN + bt * 32) * DIM;
  const int* tg = mod ? t_ir : t_rgb;
  float* rs = rowsum + mod * BATCH;
  float* tl = tgtlog + mod * BATCH;

  __shared__ __align__(16) unsigned short As[2][BM * BK];  // 16 KB
  __shared__ __align__(16) unsigned short Bs[2][BN * BK];  // 16 KB

  const int tid  = threadIdx.x;
  const int wid  = tid >> 6;
  const int lane = tid & 63;
  const int wr = wid >> 1, wc = wid & 1;
  const int l15 = lane & 15, lhi = lane >> 4;
  const int sw = (l15 & 6) << 3;       // read-side bank-spread XOR (bytes)

  f32x4 acc[4][4];
#pragma unroll
  for (int m = 0; m < 4; ++m)
#pragma unroll
    for (int n = 0; n < 4; ++n) acc[m][n] = (f32x4){0.f, 0.f, 0.f, 0.f};

  // A: verified swizzle pair — source chunk cs=(q&3)^((q>>3)&3) into linear
  // dest, read with byte^sw below (R8-R12: SQ_LDS_BANK_CONFLICT = 0).
  auto A_STAGE = [&](int buf, int kt) {
#pragma unroll
    for (int c = 0; c < 2; ++c) {
      int q = c * 256 + tid;                    // 16B chunk 0..511
      int cs = (q & 3) ^ ((q >> 3) & 3);
      gload16(X + (size_t)(q >> 2) * DIM + kt * BK + cs * 8,
              &As[buf][(c * 256 + wid * 64) * 8]);
    }
  };
  // B: f32 panel rows -> regs (issue early)
  auto B_LOAD = [&](f32x4* br, int kk) {
#pragma unroll
    for (int c = 0; c < 2; ++c) {
      int h = c * 256 + tid, row = h >> 2, j = h & 3;   // bf16 16B-chunk (row,j)
      const float* sp = Ff + (size_t)row * DIM + kk + j * 8;
      br[c * 2]     = *(const f32x4*)sp;
      br[c * 2 + 1] = *(const f32x4*)(sp + 4);
    }
  };
  // pack (truncation; >100x inside error budget) + ds_write at swizzled pos
  auto B_WRITE = [&](int buf, const f32x4* br) {
#pragma unroll
    for (int c = 0; c < 2; ++c) {
      int h = c * 256 + tid, row = h >> 2, j = h & 3;
      union { bf16x8 v; unsigned int w[4]; } p;
      const unsigned int* x0 = (const unsigned int*)&br[c * 2];
      const unsigned int* x1 = (const unsigned int*)&br[c * 2 + 1];
      p.w[0] = (x0[0] >> 16) | (x0[1] & 0xFFFF0000u);
      p.w[1] = (x0[2] >> 16) | (x0[3] & 0xFFFF0000u);
      p.w[2] = (x1[0] >> 16) | (x1[1] & 0xFFFF0000u);
      p.w[3] = (x1[2] >> 16) | (x1[3] & 0xFFFF0000u);
      *(bf16x8*)((char*)&Bs[buf][0] + row * 64 + ((j ^ ((row >> 1) & 3)) << 4)) = p.v;
    }
  };
  auto LDA = [&](int buf, int row) {
    return *(const bf16x8*)((const char*)As[buf] + ((row * 64 + lhi * 16) ^ sw));
  };
  auto LDB = [&](int buf, int row) {
    return *(const bf16x8*)((const char*)Bs[buf] + ((row * 64 + lhi * 16) ^ sw));
  };
  auto COMPUTE = [&](int buf) {
    bf16x8 a[4], b[4];
#pragma unroll
    for (int n = 0; n < 4; ++n) b[n] = LDB(buf, wc * 64 + n * 16 + l15);
#pragma unroll
    for (int m = 0; m < 4; ++m) a[m] = LDA(buf, wr * 64 + m * 16 + l15);
#pragma unroll
    for (int m = 0; m < 4; ++m)
#pragma unroll
      for (int n = 0; n < 4; ++n)
        acc[m][n] = __builtin_amdgcn_mfma_f32_16x16x32_bf16(a[m], b[n], acc[m][n], 0, 0, 0);
  };

  // prologue: K-tile 0, full drain once
  {
    f32x4 br0[4];
    B_LOAD(br0, 0);
    A_STAGE(0, 0);
    B_WRITE(0, br0);
  }
  __syncthreads();

  for (int s = 0; s < KT_N; ++s) {
    const int cur = s & 1;
    // ---- issue phase (pinned before marker) ----
    const int id = s * 256 + tid;                 // copy chunk: 32 rows x 256
    const int r32 = id >> 8, col = id & 255;
    f32x4 craw = *((const f32x4*)(Fq + (size_t)r32 * DIM) + col);
    f32x4 braw[4];
    if (s + 1 < KT_N) {
      B_LOAD(braw, (s + 1) * BK);
      A_STAGE(cur ^ 1, s + 1);
    }
    __builtin_amdgcn_sched_barrier(0);
    // ---- compute on resident buffers (loads in flight above) ----
    COMPUTE(cur);
    if (s + 1 < KT_N) B_WRITE(cur ^ 1, braw);     // implicit wait retires B+copy loads
    // ---- copy store (data ready; stores are newest VMEM) ----
    {
      float* dp = Oq + (size_t)r32 * DIM + (size_t)col * 4;
      __builtin_nontemporal_store((f32x2){craw.x, craw.y}, (f32x2*)dp);
      __builtin_nontemporal_store((f32x2){craw.z, craw.w}, (f32x2*)(dp + 2));
    }
    if (s + 1 < KT_N) {
      // counted gate: retire A-stage (2), keep the 2 copy-stores in flight
      asm volatile("s_waitcnt vmcnt(2) lgkmcnt(0)" ::: "memory");
      __builtin_amdgcn_sched_barrier(0);
      __builtin_amdgcn_s_barrier();
    }
  }

  // epilogue: exp-sum over this tile's 128 cols + target capture (verified)
#pragma unroll
  for (int m = 0; m < 4; ++m) {
    const int browbase = bt * BM + wr * 64 + m * 16 + lhi * 4;
    float esum[4];
#pragma unroll
    for (int j = 0; j < 4; ++j) {
      const int brow = browbase + j;
      const int t = tg[brow];
      float e = 0.f;
#pragma unroll
      for (int n = 0; n < 4; ++n) {
        float logit = acc[m][n][j] * TINV;
        e += __expf(logit);
        int col = nt * BN + wc * 64 + n * 16 + l15;
        if (col == t) tl[brow] = logit;
      }
      esum[j] = e;
    }
#pragma unroll
    for (int j = 0; j < 4; ++j) {
      float e = esum[j];
      e += __shfl_xor(e, 1, 64);
      e += __shfl_xor(e, 2, 64);
      e += __shfl_xor(e, 4, 64);
      e += __shfl_xor(e, 8, 64);
      if (l15 == 0) atomicAdd(rs + browbase + j, e);
    }
  }
}

// ---------------------------------------------------------------------------
// Kernel 3: loss = mean(log(rowsum) - tgtlog) per modality
// ---------------------------------------------------------------------------
__global__ void loss_kernel(const float* __restrict__ rowsum,
                            const float* __restrict__ tgtlog,
                            float* __restrict__ out) {
  int t = threadIdx.x;  // 512
  float lr = logf(rowsum[t]) - tgtlog[t];
  float li = logf(rowsum[BATCH + t]) - tgtlog[BATCH + t];
#pragma unroll
  for (int m = 1; m < 64; m <<= 1) { lr += __shfl_xor(lr, m, 64); li += __shfl_xor(li, m, 64); }
  __shared__ float sr[8], si[8];
  if ((t & 63) == 0) { sr[t >> 6] = lr; si[t >> 6] = li; }
  __syncthreads();
  if (t == 0) {
    float a = 0.f, b = 0.f;
#pragma unroll
    for (int i = 0; i < 8; ++i) { a += sr[i]; b += si[i]; }
    out[0] = a * (1.0f / BATCH);
    out[1] = b * (1.0f / BATCH);
  }
}

// ---------------------------------------------------------------------------
// Kernel 4: sequential momentum update chains on the copied banks.
// ---------------------------------------------------------------------------
__global__ void mom_kernel(const int* __restrict__ t_rgb,
                           const int* __restrict__ t_ir,
                           const float* __restrict__ xf,   // [2][512][1024]
                           float* __restrict__ out) {      // out + 2 base
  const int i   = blockIdx.x;
  const int mod = blockIdx.y;
  const int* tg = mod ? t_ir : t_rgb;
  const int y = tg[i];
  for (int j = 0; j < i; ++j)
    if (tg[j] == y) return;          // uniform: another block owns this chain

  const float* x = xf + (size_t)mod * BATCH * DIM;
  float* rowp = out + (size_t)mod * NCLUS * DIM + (size_t)y * DIM;

  const int t = threadIdx.x;  // 256
  float2 r0 = ((const float2*)rowp)[t];
  float2 r1 = ((const float2*)rowp)[t + 256];
  __shared__ float red[4];

  for (int j = i; j < BATCH; ++j) {
    if (tg[j] != y) continue;        // uniform
    const float2* xr = (const float2*)(x + (size_t)j * DIM);
    float2 x0 = xr[t], x1 = xr[t + 256];
    r0.x = 0.9f * r0.x + 0.1f * x0.x;
    r0.y = 0.9f * r0.y + 0.1f * x0.y;
    r1.x = 0.9f * r1.x + 0.1f * x1.x;
    r1.y = 0.9f * r1.y + 0.1f * x1.y;
    float ss = r0.x*r0.x + r0.y*r0.y + r1.x*r1.x + r1.y*r1.y;
#pragma unroll
    for (int m = 1; m < 64; m <<= 1) ss += __shfl_xor(ss, m, 64);
    if ((t & 63) == 0) red[t >> 6] = ss;
    __syncthreads();
    float tot = red[0] + red[1] + red[2] + red[3];
    __syncthreads();
    float inv = 1.0f / sqrtf(tot);
    r0.x *= inv; r0.y *= inv; r1.x *= inv; r1.y *= inv;
  }
  ((float2*)rowp)[t] = r0;
  ((float2*)rowp)[t + 256] = r1;
}

// ---------------------------------------------------------------------------
extern "C" void kernel_launch(void* const* d_in, const int* in_sizes, int n_in,
                              void* d_out, int out_size, void* d_ws, size_t ws_size,
                              hipStream_t stream) {
  (void)in_sizes; (void)n_in; (void)out_size; (void)ws_size;
  const float* in_rgb = (const float*)d_in[0];
  const float* in_ir  = (const float*)d_in[1];
  const int*   t_rgb  = (const int*)d_in[2];
  const int*   t_ir   = (const int*)d_in[3];
  const float* f_rgb  = (const float*)d_in[4];
  const float* f_ir   = (const float*)d_in[5];
  float* out = (float*)d_out;

  char* ws = (char*)d_ws;
  float*          xf     = (float*)ws;                       // 4 MB  [2][512][1024] f32
  unsigned short* xb     = (unsigned short*)(ws + (4u<<20)); // 2 MB  [2][512][1024] bf16
  float*          rowsum = (float*)(ws + (6u<<20));          // 2048 f32 (rowsum+tgtlog)
  float*          tgtlog = rowsum + 1024;

  nrm_kernel<<<1024, 256, 0, stream>>>(in_rgb, in_ir, xf, xb, rowsum);
  gemm_lse_kernel<<<dim3(128, 8), 256, 0, stream>>>(xb, f_rgb, f_ir, t_rgb, t_ir,
                                                    out + 2, rowsum, tgtlog);
  mom_kernel<<<dim3(512, 2), 256, 0, stream>>>(t_rgb, t_ir, xf, out + 2);
  loss_kernel<<<1, 512, 0, stream>>>(rowsum, tgtlog, out);
}